// Round 1
// baseline (3030.053 us; speedup 1.0000x reference)
//
#include <hip/hip_runtime.h>
#include <hip/hip_bf16.h>
#include <math.h>

#define B_   2
#define S_   1024
#define D_   1024
#define H_   16
#define HD_  64
#define NL_  6
#define DFF_ 4096

typedef __bf16 bf16_t;
typedef bf16_t bf16x8 __attribute__((ext_vector_type(8)));
typedef bf16_t bf16x4 __attribute__((ext_vector_type(4)));
typedef float  f32x4  __attribute__((ext_vector_type(4)));

__device__ __forceinline__ float gelu_exact(float x) {
    return 0.5f * x * (1.0f + erff(x * 0.70710678118654752f));
}

// ---------------- y = x + pos (pos broadcast over batch) ----------------
__global__ __launch_bounds__(256) void add_pos_kernel(
    const float* __restrict__ x, const float* __restrict__ pos,
    float* __restrict__ y)
{
    int idx = blockIdx.x * 256 + threadIdx.x;      // float4 index, [0, 524288)
    f32x4 xv = *(const f32x4*)&x[idx * 4];
    f32x4 pv = *(const f32x4*)&pos[(idx & 262143) * 4];  // S*D/4 = 262144
    *(f32x4*)&y[idx * 4] = xv + pv;
}

// ---------------- QKV projection: per-head 64x64 shared weights ----------------
// rows = (b,s,h) flat; each thread owns one row.
__global__ __launch_bounds__(256) void qkv_kernel(
    const float* __restrict__ y,
    const float* __restrict__ Wq, const float* __restrict__ bq,
    const float* __restrict__ Wk, const float* __restrict__ bk,
    const float* __restrict__ Wv, const float* __restrict__ bv,
    float* __restrict__ q, float* __restrict__ k, float* __restrict__ v)
{
    __shared__ float WqL[64 * 64], WkL[64 * 64], WvL[64 * 64];
    int tid = threadIdx.x;
    for (int it = 0; it < 16; ++it) {
        int i = it * 256 + tid;
        WqL[i] = Wq[i]; WkL[i] = Wk[i]; WvL[i] = Wv[i];
    }
    __syncthreads();

    long row = (long)blockIdx.x * 256 + tid;   // [0, B*S*H)
    const float* yr = y + row * 64;
    float x[64];
#pragma unroll
    for (int j = 0; j < 64; j += 4) *(f32x4*)&x[j] = *(const f32x4*)&yr[j];

#pragma unroll 1
    for (int c4 = 0; c4 < 64; c4 += 4) {
        f32x4 aq = *(const f32x4*)&bq[c4];
        f32x4 ak = *(const f32x4*)&bk[c4];
        f32x4 av = *(const f32x4*)&bv[c4];
#pragma unroll
        for (int j = 0; j < 64; ++j) {
            float xj = x[j];
            aq += xj * *(const f32x4*)&WqL[j * 64 + c4];
            ak += xj * *(const f32x4*)&WkL[j * 64 + c4];
            av += xj * *(const f32x4*)&WvL[j * 64 + c4];
        }
        *(f32x4*)&q[row * 64 + c4] = aq;
        *(f32x4*)&k[row * 64 + c4] = ak;
        *(f32x4*)&v[row * 64 + c4] = av;
    }
}

// ---------------- causal flash attention, fp32, 64q x 32k tiles ----------------
// grid: (S/64, B*H), block 256. thread: ty=tid>>4 (q group of 4), tx=tid&15 (k pair / d quad)
__global__ __launch_bounds__(256) void attn_kernel(
    const float* __restrict__ Q, const float* __restrict__ K,
    const float* __restrict__ V, bf16_t* __restrict__ Ob)
{
    __shared__ float Qs[64 * 68];
    __shared__ float Ks[32 * 68];
    __shared__ float Vs[32 * 64];
    __shared__ float Ps[64 * 36];

    int tid = threadIdx.x;
    int tx = tid & 15, ty = tid >> 4;
    int qt = blockIdx.x;
    int bh = blockIdx.y;
    int b = bh >> 4, h = bh & 15;
    int q0 = qt * 64;
    const float scale = 0.125f;   // 1/sqrt(64)

    for (int it = 0; it < 4; ++it) {
        int c = it * 256 + tid;            // [0,1024)
        int row = c >> 4, col = (c & 15) * 4;
        *(f32x4*)&Qs[row * 68 + col] =
            *(const f32x4*)&Q[(((long)b * S_ + q0 + row) * H_ + h) * HD_ + col];
    }

    float mrun[4], lrun[4];
    f32x4 oacc[4];
#pragma unroll
    for (int r = 0; r < 4; ++r) { mrun[r] = -3.0e38f; lrun[r] = 0.f; oacc[r] = (f32x4)0.f; }

    int nkt = (q0 + 64) / 32;
    for (int kt = 0; kt < nkt; ++kt) {
        int k0 = kt * 32;
        __syncthreads();
        for (int it = 0; it < 2; ++it) {
            int c = it * 256 + tid;        // [0,512)
            int row = c >> 4, col = (c & 15) * 4;
            *(f32x4*)&Ks[row * 68 + col] =
                *(const f32x4*)&K[(((long)b * S_ + k0 + row) * H_ + h) * HD_ + col];
            *(f32x4*)&Vs[row * 64 + col] =
                *(const f32x4*)&V[(((long)b * S_ + k0 + row) * H_ + h) * HD_ + col];
        }
        __syncthreads();

        // scores: q = ty*4+rq, k = tx*2+rk
        f32x4 dv[4][2];
#pragma unroll
        for (int rq = 0; rq < 4; ++rq) { dv[rq][0] = (f32x4)0.f; dv[rq][1] = (f32x4)0.f; }
#pragma unroll
        for (int j = 0; j < 64; j += 4) {
            f32x4 kv0 = *(f32x4*)&Ks[(tx * 2 + 0) * 68 + j];
            f32x4 kv1 = *(f32x4*)&Ks[(tx * 2 + 1) * 68 + j];
#pragma unroll
            for (int rq = 0; rq < 4; ++rq) {
                f32x4 qv = *(f32x4*)&Qs[(ty * 4 + rq) * 68 + j];
                dv[rq][0] += qv * kv0;
                dv[rq][1] += qv * kv1;
            }
        }
#pragma unroll
        for (int rq = 0; rq < 4; ++rq) {
            int qg = q0 + ty * 4 + rq;
            float s0 = dv[rq][0][0] + dv[rq][0][1] + dv[rq][0][2] + dv[rq][0][3];
            float s1 = dv[rq][1][0] + dv[rq][1][1] + dv[rq][1][2] + dv[rq][1][3];
            int kg0 = k0 + tx * 2;
            s0 = (kg0     <= qg) ? s0 * scale : -3.0e38f;
            s1 = (kg0 + 1 <= qg) ? s1 * scale : -3.0e38f;
            float mt = fmaxf(s0, s1);
            mt = fmaxf(mt, __shfl_xor(mt, 1));
            mt = fmaxf(mt, __shfl_xor(mt, 2));
            mt = fmaxf(mt, __shfl_xor(mt, 4));
            mt = fmaxf(mt, __shfl_xor(mt, 8));
            float mnew = fmaxf(mrun[rq], mt);
            float p0 = __expf(s0 - mnew);
            float p1 = __expf(s1 - mnew);
            float ls = p0 + p1;
            ls += __shfl_xor(ls, 1);
            ls += __shfl_xor(ls, 2);
            ls += __shfl_xor(ls, 4);
            ls += __shfl_xor(ls, 8);
            float alpha = __expf(mrun[rq] - mnew);
            lrun[rq] = lrun[rq] * alpha + ls;
            mrun[rq] = mnew;
            oacc[rq] *= alpha;
            Ps[(ty * 4 + rq) * 36 + tx * 2 + 0] = p0;
            Ps[(ty * 4 + rq) * 36 + tx * 2 + 1] = p1;
        }
        __syncthreads();

        // PV: d = tx*4..tx*4+3
#pragma unroll 4
        for (int kk = 0; kk < 32; ++kk) {
            f32x4 vv = *(f32x4*)&Vs[kk * 64 + tx * 4];
#pragma unroll
            for (int rq = 0; rq < 4; ++rq)
                oacc[rq] += Ps[(ty * 4 + rq) * 36 + kk] * vv;
        }
    }

#pragma unroll
    for (int rq = 0; rq < 4; ++rq) {
        int qg = q0 + ty * 4 + rq;
        f32x4 o = oacc[rq] * (1.0f / lrun[rq]);
        *(bf16x4*)&Ob[(((long)b * S_ + qg) * H_ + h) * HD_ + tx * 4] =
            __builtin_convertvector(o, bf16x4);
    }
}

// ---------------- transpose + fp32->bf16 convert: W[Kd x Nd] -> Wt[Nd x Kd] ----------------
__global__ void tconv_kernel(const float* __restrict__ W, bf16_t* __restrict__ Wt,
                             int Kd, int Nd)
{
    __shared__ float t[32][33];
    int tx = threadIdx.x, ty = threadIdx.y;  // (32, 8)
    int bx = blockIdx.x, by = blockIdx.y;
#pragma unroll
    for (int i = 0; i < 4; ++i)
        t[ty + i * 8][tx] = W[(size_t)(by * 32 + ty + i * 8) * Nd + bx * 32 + tx];
    __syncthreads();
#pragma unroll
    for (int i = 0; i < 4; ++i)
        Wt[(size_t)(bx * 32 + ty + i * 8) * Kd + by * 32 + tx] = (bf16_t)t[tx][ty + i * 8];
}

// ---------------- bf16 MFMA GEMM: C[MxN] = A[MxK] * Bt[NxK]^T + bias ----------------
// 128x128 tile, 4 waves (2x2), each wave 64x64 via 4x4 mfma_f32_16x16x32_bf16.
#define LDT 40
__global__ __launch_bounds__(256) void gemm_bt_kernel(
    const bf16_t* __restrict__ A, const bf16_t* __restrict__ Bt,
    const float* __restrict__ bias, float* __restrict__ Cf,
    bf16_t* __restrict__ Cb, int M, int N, int K, int act)
{
    __shared__ bf16_t As[128 * LDT];
    __shared__ bf16_t Bs[128 * LDT];
    int tid = threadIdx.x;
    int wave = tid >> 6, lane = tid & 63;
    int quad = lane >> 4, l16 = lane & 15;
    int m0 = blockIdx.x * 128;
    int n0 = blockIdx.y * 128;
    int wm = (wave >> 1) * 64, wn = (wave & 1) * 64;

    f32x4 acc[4][4];
#pragma unroll
    for (int i = 0; i < 4; ++i)
#pragma unroll
        for (int j = 0; j < 4; ++j) acc[i][j] = (f32x4)0.f;

    for (int k0 = 0; k0 < K; k0 += 32) {
        __syncthreads();
#pragma unroll
        for (int it = 0; it < 2; ++it) {
            int c = it * 256 + tid;          // [0,512)
            int row = c >> 2, col = (c & 3) * 8;
            *(bf16x8*)&As[row * LDT + col] =
                *(const bf16x8*)&A[(size_t)(m0 + row) * K + k0 + col];
            *(bf16x8*)&Bs[row * LDT + col] =
                *(const bf16x8*)&Bt[(size_t)(n0 + row) * K + k0 + col];
        }
        __syncthreads();

        bf16x8 af[4], bfr[4];
#pragma unroll
        for (int i = 0; i < 4; ++i)
            af[i] = *(bf16x8*)&As[(wm + i * 16 + l16) * LDT + quad * 8];
#pragma unroll
        for (int j = 0; j < 4; ++j)
            bfr[j] = *(bf16x8*)&Bs[(wn + j * 16 + l16) * LDT + quad * 8];
#pragma unroll
        for (int i = 0; i < 4; ++i)
#pragma unroll
            for (int j = 0; j < 4; ++j)
                acc[i][j] = __builtin_amdgcn_mfma_f32_16x16x32_bf16(
                    af[i], bfr[j], acc[i][j], 0, 0, 0);
    }

#pragma unroll
    for (int j = 0; j < 4; ++j) {
        int col = n0 + wn + j * 16 + l16;
        float bv = bias ? bias[col] : 0.f;
#pragma unroll
        for (int i = 0; i < 4; ++i) {
            int rbase = m0 + wm + i * 16 + quad * 4;
#pragma unroll
            for (int r = 0; r < 4; ++r) {
                float vv = acc[i][j][r] + bv;
                if (act == 1) vv = gelu_exact(vv);
                if (Cf) Cf[(size_t)(rbase + r) * N + col] = vv;
                if (Cb) Cb[(size_t)(rbase + r) * N + col] = (bf16_t)vv;
            }
        }
    }
}

// ---------------- fused residual add + LayerNorm (row = one block) ----------------
__global__ __launch_bounds__(256) void ln_fused_kernel(
    const float* __restrict__ a, const float* __restrict__ b,
    const float* __restrict__ w, const float* __restrict__ beta,
    float* __restrict__ out, bf16_t* __restrict__ outb)
{
    long row = blockIdx.x;
    int tid = threadIdx.x;
    f32x4 z = *(const f32x4*)&a[row * D_ + tid * 4];
    if (b) z += *(const f32x4*)&b[row * D_ + tid * 4];
    float s  = z[0] + z[1] + z[2] + z[3];
    float ss = z[0]*z[0] + z[1]*z[1] + z[2]*z[2] + z[3]*z[3];
#pragma unroll
    for (int off = 32; off >= 1; off >>= 1) {
        s  += __shfl_down(s, off);
        ss += __shfl_down(ss, off);
    }
    __shared__ float red[8];
    int lane = tid & 63, wid = tid >> 6;
    if (lane == 0) { red[wid * 2] = s; red[wid * 2 + 1] = ss; }
    __syncthreads();
    s  = red[0] + red[2] + red[4] + red[6];
    ss = red[1] + red[3] + red[5] + red[7];
    float mean = s * (1.0f / D_);
    float var  = ss * (1.0f / D_) - mean * mean;
    float rs = rsqrtf(var + 1e-5f);
    f32x4 wv = *(const f32x4*)&w[tid * 4];
    f32x4 bv = *(const f32x4*)&beta[tid * 4];
    f32x4 o = (z - mean) * rs * wv + bv;
    *(f32x4*)&out[row * D_ + tid * 4] = o;
    if (outb) *(bf16x4*)&outb[row * D_ + tid * 4] = __builtin_convertvector(o, bf16x4);
}

// ---------------- host launch ----------------
extern "C" void kernel_launch(void* const* d_in, const int* in_sizes, int n_in,
                              void* d_out, int out_size, void* d_ws, size_t ws_size,
                              hipStream_t stream)
{
    (void)in_sizes; (void)n_in; (void)out_size; (void)ws_size;
    const float* x    = (const float*)d_in[0];
    const float* pos  = (const float*)d_in[1];
    const float* Wq   = (const float*)d_in[2];
    const float* bq   = (const float*)d_in[3];
    const float* Wk   = (const float*)d_in[4];
    const float* bk   = (const float*)d_in[5];
    const float* Wv   = (const float*)d_in[6];
    const float* bv   = (const float*)d_in[7];
    const float* Wfc  = (const float*)d_in[8];
    const float* bfc  = (const float*)d_in[9];
    const float* ln1w = (const float*)d_in[10];
    const float* ln1b = (const float*)d_in[11];
    const float* ln2w = (const float*)d_in[12];
    const float* ln2b = (const float*)d_in[13];
    const float* W1   = (const float*)d_in[14];
    const float* b1   = (const float*)d_in[15];
    const float* W2   = (const float*)d_in[16];
    const float* b2   = (const float*)d_in[17];
    const float* lnfw = (const float*)d_in[18];
    const float* lnfb = (const float*)d_in[19];

    const size_t MB = 1 << 20;
    char* ws = (char*)d_ws;
    float*  y    = (float*)(ws);             //  8 MB
    float*  q    = (float*)(ws + 8 * MB);    //  8 MB (reused as t1)
    float*  k    = (float*)(ws + 16 * MB);   //  8 MB (reused as t2)
    float*  v    = (float*)(ws + 24 * MB);   //  8 MB
    float*  add  = (float*)(ws + 32 * MB);   //  8 MB
    bf16_t* ob   = (bf16_t*)(ws + 40 * MB);  //  4 MB
    bf16_t* addb = (bf16_t*)(ws + 44 * MB);  //  4 MB
    bf16_t* ffb  = (bf16_t*)(ws + 48 * MB);  // 16 MB
    bf16_t* WT   = (bf16_t*)(ws + 64 * MB);  //  8 MB (per-layer reuse)
    float* t1 = q;
    float* t2 = k;

    add_pos_kernel<<<2048, 256, 0, stream>>>(x, pos, y);

    for (int i = 0; i < NL_; ++i) {
        qkv_kernel<<<128, 256, 0, stream>>>(
            y, Wq + i * 4096, bq + i * 64, Wk + i * 4096, bk + i * 64,
            Wv + i * 4096, bv + i * 64, q, k, v);

        attn_kernel<<<dim3(16, 32), 256, 0, stream>>>(q, k, v, ob);

        tconv_kernel<<<dim3(32, 32), dim3(32, 8), 0, stream>>>(
            Wfc + (size_t)i * D_ * D_, WT, D_, D_);
        gemm_bt_kernel<<<dim3(16, 8), 256, 0, stream>>>(
            ob, WT, bfc + i * D_, t1, nullptr, 2048, D_, D_, 0);

        ln_fused_kernel<<<2048, 256, 0, stream>>>(
            t1, y, ln1w + i * D_, ln1b + i * D_, add, addb);

        tconv_kernel<<<dim3(128, 32), dim3(32, 8), 0, stream>>>(
            W1 + (size_t)i * D_ * DFF_, WT, D_, DFF_);
        gemm_bt_kernel<<<dim3(16, 32), 256, 0, stream>>>(
            addb, WT, b1 + i * DFF_, nullptr, ffb, 2048, DFF_, D_, 1);

        tconv_kernel<<<dim3(32, 128), dim3(32, 8), 0, stream>>>(
            W2 + (size_t)i * DFF_ * D_, WT, DFF_, D_);
        gemm_bt_kernel<<<dim3(16, 8), 256, 0, stream>>>(
            ffb, WT, b2 + i * D_, t2, nullptr, 2048, D_, DFF_, 0);

        ln_fused_kernel<<<2048, 256, 0, stream>>>(
            t2, add, ln2w + i * D_, ln2b + i * D_, y, nullptr);
    }

    ln_fused_kernel<<<2048, 256, 0, stream>>>(
        y, nullptr, lnfw, lnfb, (float*)d_out, nullptr);
}

// Round 2
// 2337.399 us; speedup vs baseline: 1.2963x; 1.2963x over previous
//
#include <hip/hip_runtime.h>
#include <hip/hip_bf16.h>
#include <math.h>

#define B_   2
#define S_   1024
#define D_   1024
#define H_   16
#define HD_  64
#define NL_  6
#define DFF_ 4096

typedef __bf16 bf16_t;
typedef bf16_t bf16x8 __attribute__((ext_vector_type(8)));
typedef bf16_t bf16x4 __attribute__((ext_vector_type(4)));
typedef float  f32x4  __attribute__((ext_vector_type(4)));

__device__ __forceinline__ float gelu_exact(float x) {
    return 0.5f * x * (1.0f + erff(x * 0.70710678118654752f));
}

// ---------------- y = x + pos (pos broadcast over batch) ----------------
__global__ __launch_bounds__(256) void add_pos_kernel(
    const float* __restrict__ x, const float* __restrict__ pos,
    float* __restrict__ y)
{
    int idx = blockIdx.x * 256 + threadIdx.x;      // float4 index, [0, 524288)
    f32x4 xv = *(const f32x4*)&x[idx * 4];
    f32x4 pv = *(const f32x4*)&pos[(idx & 262143) * 4];  // S*D/4 = 262144
    *(f32x4*)&y[idx * 4] = xv + pv;
}

// ---------------- QKV projection: per-head 64x64 shared weights ----------------
// rows = (b,s,h) flat; each thread owns one row. fp32 compute, bf16 stores.
__global__ __launch_bounds__(256) void qkv_kernel(
    const float* __restrict__ y,
    const float* __restrict__ Wq, const float* __restrict__ bq,
    const float* __restrict__ Wk, const float* __restrict__ bk,
    const float* __restrict__ Wv, const float* __restrict__ bv,
    bf16_t* __restrict__ q, bf16_t* __restrict__ k, bf16_t* __restrict__ v)
{
    __shared__ float WqL[64 * 64], WkL[64 * 64], WvL[64 * 64];
    int tid = threadIdx.x;
    for (int it = 0; it < 16; ++it) {
        int i = it * 256 + tid;
        WqL[i] = Wq[i]; WkL[i] = Wk[i]; WvL[i] = Wv[i];
    }
    __syncthreads();

    long row = (long)blockIdx.x * 256 + tid;   // [0, B*S*H)
    const float* yr = y + row * 64;
    float x[64];
#pragma unroll
    for (int j = 0; j < 64; j += 4) *(f32x4*)&x[j] = *(const f32x4*)&yr[j];

#pragma unroll 1
    for (int c4 = 0; c4 < 64; c4 += 4) {
        f32x4 aq = *(const f32x4*)&bq[c4];
        f32x4 ak = *(const f32x4*)&bk[c4];
        f32x4 av = *(const f32x4*)&bv[c4];
#pragma unroll
        for (int j = 0; j < 64; ++j) {
            float xj = x[j];
            aq += xj * *(const f32x4*)&WqL[j * 64 + c4];
            ak += xj * *(const f32x4*)&WkL[j * 64 + c4];
            av += xj * *(const f32x4*)&WvL[j * 64 + c4];
        }
        *(bf16x4*)&q[row * 64 + c4] = __builtin_convertvector(aq, bf16x4);
        *(bf16x4*)&k[row * 64 + c4] = __builtin_convertvector(ak, bf16x4);
        *(bf16x4*)&v[row * 64 + c4] = __builtin_convertvector(av, bf16x4);
    }
}

// ---------------- causal flash attention, bf16 MFMA, 64q x 32kv tiles ----------------
// grid: (S/64, B*H), block 256 = 4 waves; wave w owns q rows q0+w*16..+15.
// mfma_f32_16x16x32_bf16: A[m=l16][k=quad*8+j], B(t)[n=l16][k=quad*8+j],
// C/D col=l16, row=quad*4+reg.
__global__ __launch_bounds__(256) void attn_mfma_kernel(
    const bf16_t* __restrict__ Q, const bf16_t* __restrict__ K,
    const bf16_t* __restrict__ V, bf16_t* __restrict__ Ob)
{
    __shared__ bf16_t Ks[32][72];       // [kv][d], pad 8
    __shared__ bf16_t Vt[64][40];       // [d][kv], pad 8
    __shared__ bf16_t Ps[4][16][40];    // per-wave P tile [q][kv], pad 8

    int tid = threadIdx.x;
    int wave = tid >> 6, lane = tid & 63;
    int quad = lane >> 4, l16 = lane & 15;
    int q0 = blockIdx.x * 64;
    int bh = blockIdx.y;
    int b = bh >> 4, h = bh & 15;
    int qw = q0 + wave * 16;
    const float scale = 0.125f;             // 1/sqrt(64)
    const float MASKED = -1.25e19f;         // -1e20 * scale, per reference order

    // Q fragments for this wave's 16 rows (once)
    const bf16_t* Qbase = Q + (((long)b * S_ + qw + l16) * H_ + h) * HD_;
    bf16x8 aq0 = *(const bf16x8*)&Qbase[quad * 8];
    bf16x8 aq1 = *(const bf16x8*)&Qbase[32 + quad * 8];

    float mrun[4], lrun[4];
    f32x4 oacc[4];
#pragma unroll
    for (int r = 0; r < 4; ++r) { mrun[r] = -3.0e38f; lrun[r] = 0.f; }
#pragma unroll
    for (int n = 0; n < 4; ++n) oacc[n] = (f32x4)0.f;

    int srow = tid >> 3, scol = (tid & 7) * 8;   // staging: 32 rows x 64 d
    int nkt = (q0 + 64) / 32;
    for (int kt = 0; kt < nkt; ++kt) {
        int k0 = kt * 32;
        __syncthreads();
        {
            long base = (((long)b * S_ + k0 + srow) * H_ + h) * HD_ + scol;
            *(bf16x8*)&Ks[srow][scol] = *(const bf16x8*)&K[base];
            bf16x8 vv = *(const bf16x8*)&V[base];
#pragma unroll
            for (int j = 0; j < 8; ++j) Vt[scol + j][srow] = vv[j];
        }
        __syncthreads();

        // ---- QK^T: S[16q x 32kv] ----
        f32x4 sc[2];
        sc[0] = (f32x4)0.f; sc[1] = (f32x4)0.f;
#pragma unroll
        for (int n = 0; n < 2; ++n) {
            bf16x8 bk0 = *(bf16x8*)&Ks[n * 16 + l16][quad * 8];
            bf16x8 bk1 = *(bf16x8*)&Ks[n * 16 + l16][32 + quad * 8];
            sc[n] = __builtin_amdgcn_mfma_f32_16x16x32_bf16(aq0, bk0, sc[n], 0, 0, 0);
            sc[n] = __builtin_amdgcn_mfma_f32_16x16x32_bf16(aq1, bk1, sc[n], 0, 0, 0);
        }

        // ---- online softmax (fp32). lane: rows qw+quad*4+r, cols k0+n*16+l16 ----
        float alpha[4];
#pragma unroll
        for (int r = 0; r < 4; ++r) {
            int qg = qw + quad * 4 + r;
            float s0 = (k0 + l16      <= qg) ? sc[0][r] * scale : MASKED;
            float s1 = (k0 + 16 + l16 <= qg) ? sc[1][r] * scale : MASKED;
            float mt = fmaxf(s0, s1);
            mt = fmaxf(mt, __shfl_xor(mt, 1));
            mt = fmaxf(mt, __shfl_xor(mt, 2));
            mt = fmaxf(mt, __shfl_xor(mt, 4));
            mt = fmaxf(mt, __shfl_xor(mt, 8));
            float mnew = fmaxf(mrun[r], mt);
            float p0 = __expf(s0 - mnew);
            float p1 = __expf(s1 - mnew);
            float ls = p0 + p1;
            ls += __shfl_xor(ls, 1);
            ls += __shfl_xor(ls, 2);
            ls += __shfl_xor(ls, 4);
            ls += __shfl_xor(ls, 8);
            alpha[r] = __expf(mrun[r] - mnew);
            lrun[r] = lrun[r] * alpha[r] + ls;
            mrun[r] = mnew;
            int prow = quad * 4 + r;
            Ps[wave][prow][l16]      = (bf16_t)p0;
            Ps[wave][prow][16 + l16] = (bf16_t)p1;
        }
        // wave-local LDS round-trip (no barrier needed: same wave wrote it)
        bf16x8 ap = *(bf16x8*)&Ps[wave][l16][quad * 8];

        // ---- PV: O[16q x 64d] += P * V ----
#pragma unroll
        for (int n = 0; n < 4; ++n) {
            bf16x8 bv = *(bf16x8*)&Vt[n * 16 + l16][quad * 8];
            f32x4 c = oacc[n];
#pragma unroll
            for (int r = 0; r < 4; ++r) c[r] *= alpha[r];
            oacc[n] = __builtin_amdgcn_mfma_f32_16x16x32_bf16(ap, bv, c, 0, 0, 0);
        }
    }

    // epilogue: divide by l, store bf16. col=n*16+l16 (d), row=quad*4+r (q)
#pragma unroll
    for (int r = 0; r < 4; ++r) {
        float inv = 1.0f / lrun[r];
        long rowbase = (((long)b * S_ + qw + quad * 4 + r) * H_ + h) * HD_;
#pragma unroll
        for (int n = 0; n < 4; ++n)
            Ob[rowbase + n * 16 + l16] = (bf16_t)(oacc[n][r] * inv);
    }
}

// ---------------- transpose + fp32->bf16 convert: W[Kd x Nd] -> Wt[Nd x Kd] ----------------
__global__ void tconv_kernel(const float* __restrict__ W, bf16_t* __restrict__ Wt,
                             int Kd, int Nd)
{
    __shared__ float t[32][33];
    int tx = threadIdx.x, ty = threadIdx.y;  // (32, 8)
    int bx = blockIdx.x, by = blockIdx.y;
#pragma unroll
    for (int i = 0; i < 4; ++i)
        t[ty + i * 8][tx] = W[(size_t)(by * 32 + ty + i * 8) * Nd + bx * 32 + tx];
    __syncthreads();
#pragma unroll
    for (int i = 0; i < 4; ++i)
        Wt[(size_t)(bx * 32 + ty + i * 8) * Kd + by * 32 + tx] = (bf16_t)t[tx][ty + i * 8];
}

// ---------------- bf16 MFMA GEMM: C[MxN] = A[MxK] * Bt[NxK]^T + bias ----------------
// 128x128 tile, 4 waves (2x2), each wave 64x64 via 4x4 mfma_f32_16x16x32_bf16.
#define LDT 40
__global__ __launch_bounds__(256) void gemm_bt_kernel(
    const bf16_t* __restrict__ A, const bf16_t* __restrict__ Bt,
    const float* __restrict__ bias, float* __restrict__ Cf,
    bf16_t* __restrict__ Cb, int M, int N, int K, int act)
{
    __shared__ bf16_t As[128 * LDT];
    __shared__ bf16_t Bs[128 * LDT];
    int tid = threadIdx.x;
    int wave = tid >> 6, lane = tid & 63;
    int quad = lane >> 4, l16 = lane & 15;
    int m0 = blockIdx.x * 128;
    int n0 = blockIdx.y * 128;
    int wm = (wave >> 1) * 64, wn = (wave & 1) * 64;

    f32x4 acc[4][4];
#pragma unroll
    for (int i = 0; i < 4; ++i)
#pragma unroll
        for (int j = 0; j < 4; ++j) acc[i][j] = (f32x4)0.f;

    for (int k0 = 0; k0 < K; k0 += 32) {
        __syncthreads();
#pragma unroll
        for (int it = 0; it < 2; ++it) {
            int c = it * 256 + tid;          // [0,512)
            int row = c >> 2, col = (c & 3) * 8;
            *(bf16x8*)&As[row * LDT + col] =
                *(const bf16x8*)&A[(size_t)(m0 + row) * K + k0 + col];
            *(bf16x8*)&Bs[row * LDT + col] =
                *(const bf16x8*)&Bt[(size_t)(n0 + row) * K + k0 + col];
        }
        __syncthreads();

        bf16x8 af[4], bfr[4];
#pragma unroll
        for (int i = 0; i < 4; ++i)
            af[i] = *(bf16x8*)&As[(wm + i * 16 + l16) * LDT + quad * 8];
#pragma unroll
        for (int j = 0; j < 4; ++j)
            bfr[j] = *(bf16x8*)&Bs[(wn + j * 16 + l16) * LDT + quad * 8];
#pragma unroll
        for (int i = 0; i < 4; ++i)
#pragma unroll
            for (int j = 0; j < 4; ++j)
                acc[i][j] = __builtin_amdgcn_mfma_f32_16x16x32_bf16(
                    af[i], bfr[j], acc[i][j], 0, 0, 0);
    }

#pragma unroll
    for (int j = 0; j < 4; ++j) {
        int col = n0 + wn + j * 16 + l16;
        float bv = bias ? bias[col] : 0.f;
#pragma unroll
        for (int i = 0; i < 4; ++i) {
            int rbase = m0 + wm + i * 16 + quad * 4;
#pragma unroll
            for (int r = 0; r < 4; ++r) {
                float vv = acc[i][j][r] + bv;
                if (act == 1) vv = gelu_exact(vv);
                if (Cf) Cf[(size_t)(rbase + r) * N + col] = vv;
                if (Cb) Cb[(size_t)(rbase + r) * N + col] = (bf16_t)vv;
            }
        }
    }
}

// ---------------- fused residual add + LayerNorm (row = one block) ----------------
__global__ __launch_bounds__(256) void ln_fused_kernel(
    const float* __restrict__ a, const float* __restrict__ b,
    const float* __restrict__ w, const float* __restrict__ beta,
    float* __restrict__ out, bf16_t* __restrict__ outb)
{
    long row = blockIdx.x;
    int tid = threadIdx.x;
    f32x4 z = *(const f32x4*)&a[row * D_ + tid * 4];
    if (b) z += *(const f32x4*)&b[row * D_ + tid * 4];
    float s  = z[0] + z[1] + z[2] + z[3];
    float ss = z[0]*z[0] + z[1]*z[1] + z[2]*z[2] + z[3]*z[3];
#pragma unroll
    for (int off = 32; off >= 1; off >>= 1) {
        s  += __shfl_down(s, off);
        ss += __shfl_down(ss, off);
    }
    __shared__ float red[8];
    int lane = tid & 63, wid = tid >> 6;
    if (lane == 0) { red[wid * 2] = s; red[wid * 2 + 1] = ss; }
    __syncthreads();
    s  = red[0] + red[2] + red[4] + red[6];
    ss = red[1] + red[3] + red[5] + red[7];
    float mean = s * (1.0f / D_);
    float var  = ss * (1.0f / D_) - mean * mean;
    float rs = rsqrtf(var + 1e-5f);
    f32x4 wv = *(const f32x4*)&w[tid * 4];
    f32x4 bv = *(const f32x4*)&beta[tid * 4];
    f32x4 o = (z - mean) * rs * wv + bv;
    *(f32x4*)&out[row * D_ + tid * 4] = o;
    if (outb) *(bf16x4*)&outb[row * D_ + tid * 4] = __builtin_convertvector(o, bf16x4);
}

// ---------------- host launch ----------------
extern "C" void kernel_launch(void* const* d_in, const int* in_sizes, int n_in,
                              void* d_out, int out_size, void* d_ws, size_t ws_size,
                              hipStream_t stream)
{
    (void)in_sizes; (void)n_in; (void)out_size; (void)ws_size;
    const float* x    = (const float*)d_in[0];
    const float* pos  = (const float*)d_in[1];
    const float* Wq   = (const float*)d_in[2];
    const float* bq   = (const float*)d_in[3];
    const float* Wk   = (const float*)d_in[4];
    const float* bk   = (const float*)d_in[5];
    const float* Wv   = (const float*)d_in[6];
    const float* bv   = (const float*)d_in[7];
    const float* Wfc  = (const float*)d_in[8];
    const float* bfc  = (const float*)d_in[9];
    const float* ln1w = (const float*)d_in[10];
    const float* ln1b = (const float*)d_in[11];
    const float* ln2w = (const float*)d_in[12];
    const float* ln2b = (const float*)d_in[13];
    const float* W1   = (const float*)d_in[14];
    const float* b1   = (const float*)d_in[15];
    const float* W2   = (const float*)d_in[16];
    const float* b2   = (const float*)d_in[17];
    const float* lnfw = (const float*)d_in[18];
    const float* lnfb = (const float*)d_in[19];

    const size_t MB = 1 << 20;
    char* ws = (char*)d_ws;
    float*  y    = (float*)(ws);             //  8 MB
    bf16_t* qb   = (bf16_t*)(ws + 8 * MB);   //  4 MB
    bf16_t* kb   = (bf16_t*)(ws + 12 * MB);  //  4 MB
    bf16_t* vb   = (bf16_t*)(ws + 16 * MB);  //  4 MB (+4 spare for t2)
    float*  t1   = (float*)(ws + 8 * MB);    //  8 MB (aliases qb/kb after attn)
    float*  t2   = (float*)(ws + 16 * MB);   //  8 MB (aliases vb+spare after attn)
    float*  add  = (float*)(ws + 24 * MB);   //  8 MB
    bf16_t* ob   = (bf16_t*)(ws + 32 * MB);  //  4 MB
    bf16_t* addb = (bf16_t*)(ws + 36 * MB);  //  4 MB
    bf16_t* ffb  = (bf16_t*)(ws + 40 * MB);  // 16 MB
    bf16_t* WT   = (bf16_t*)(ws + 56 * MB);  //  8 MB (per-layer reuse)

    add_pos_kernel<<<2048, 256, 0, stream>>>(x, pos, y);

    for (int i = 0; i < NL_; ++i) {
        qkv_kernel<<<128, 256, 0, stream>>>(
            y, Wq + i * 4096, bq + i * 64, Wk + i * 4096, bk + i * 64,
            Wv + i * 4096, bv + i * 64, qb, kb, vb);

        attn_mfma_kernel<<<dim3(16, 32), 256, 0, stream>>>(qb, kb, vb, ob);

        tconv_kernel<<<dim3(32, 32), dim3(32, 8), 0, stream>>>(
            Wfc + (size_t)i * D_ * D_, WT, D_, D_);
        gemm_bt_kernel<<<dim3(16, 8), 256, 0, stream>>>(
            ob, WT, bfc + i * D_, t1, nullptr, 2048, D_, D_, 0);

        ln_fused_kernel<<<2048, 256, 0, stream>>>(
            t1, y, ln1w + i * D_, ln1b + i * D_, add, addb);

        tconv_kernel<<<dim3(128, 32), dim3(32, 8), 0, stream>>>(
            W1 + (size_t)i * D_ * DFF_, WT, D_, DFF_);
        gemm_bt_kernel<<<dim3(16, 32), 256, 0, stream>>>(
            addb, WT, b1 + i * DFF_, nullptr, ffb, 2048, DFF_, D_, 1);

        tconv_kernel<<<dim3(32, 128), dim3(32, 8), 0, stream>>>(
            W2 + (size_t)i * DFF_ * D_, WT, DFF_, D_);
        gemm_bt_kernel<<<dim3(16, 8), 256, 0, stream>>>(
            ffb, WT, b2 + i * D_, t2, nullptr, 2048, D_, DFF_, 0);

        ln_fused_kernel<<<2048, 256, 0, stream>>>(
            t2, add, ln2w + i * D_, ln2b + i * D_, y, nullptr);
    }

    ln_fused_kernel<<<2048, 256, 0, stream>>>(
        y, nullptr, lnfw, lnfb, (float*)d_out, nullptr);
}

// Round 3
// 1771.077 us; speedup vs baseline: 1.7109x; 1.3198x over previous
//
#include <hip/hip_runtime.h>
#include <hip/hip_bf16.h>
#include <math.h>

#define B_   2
#define S_   1024
#define D_   1024
#define H_   16
#define HD_  64
#define NL_  6
#define DFF_ 4096

typedef __bf16 bf16_t;
typedef bf16_t bf16x8 __attribute__((ext_vector_type(8)));
typedef bf16_t bf16x4 __attribute__((ext_vector_type(4)));
typedef float  f32x4  __attribute__((ext_vector_type(4)));

__device__ __forceinline__ float gelu_exact(float x) {
    return 0.5f * x * (1.0f + erff(x * 0.70710678118654752f));
}

// ---------------- y = x + pos (pos broadcast over batch); fp32 + bf16 out ----------------
__global__ __launch_bounds__(256) void add_pos_kernel(
    const float* __restrict__ x, const float* __restrict__ pos,
    float* __restrict__ y, bf16_t* __restrict__ yb)
{
    int idx = blockIdx.x * 256 + threadIdx.x;      // float4 index, [0, 524288)
    f32x4 xv = *(const f32x4*)&x[idx * 4];
    f32x4 pv = *(const f32x4*)&pos[(idx & 262143) * 4];  // S*D/4 = 262144
    f32x4 o = xv + pv;
    *(f32x4*)&y[idx * 4] = o;
    *(bf16x4*)&yb[idx * 4] = __builtin_convertvector(o, bf16x4);
}

// ---------------- QKV projection via MFMA ----------------
// yb viewed as (B*S*H, 64); q/k/v = yb @ W{q,k,v}(64x64) + b (weights shared over heads).
// grid 256 blocks x 256 thr (4 waves); block tile M=128, N=64, K=64; wave tile 32x64.
__global__ __launch_bounds__(256) void qkv_mfma_kernel(
    const bf16_t* __restrict__ yb,
    const float* __restrict__ Wq, const float* __restrict__ bq,
    const float* __restrict__ Wk, const float* __restrict__ bk,
    const float* __restrict__ Wv, const float* __restrict__ bv,
    bf16_t* __restrict__ q, bf16_t* __restrict__ k, bf16_t* __restrict__ v)
{
    __shared__ bf16_t As[128][72];
    __shared__ bf16_t Wt[3][64][72];   // W^T: [n][k], bf16

    int tid = threadIdx.x;
    long m0 = (long)blockIdx.x * 128;

#pragma unroll
    for (int it = 0; it < 4; ++it) {
        int c = it * 256 + tid;            // [0,1024) x8 elems
        int row = c >> 3, col = (c & 7) * 8;
        *(bf16x8*)&As[row][col] = *(const bf16x8*)&yb[(m0 + row) * 64 + col];
    }
#pragma unroll
    for (int it = 0; it < 16; ++it) {
        int i = it * 256 + tid;            // [0,4096)
        int r = i >> 6, c = i & 63;
        Wt[0][c][r] = (bf16_t)Wq[i];
        Wt[1][c][r] = (bf16_t)Wk[i];
        Wt[2][c][r] = (bf16_t)Wv[i];
    }
    __syncthreads();

    int wave = tid >> 6, lane = tid & 63;
    int quad = lane >> 4, l16 = lane & 15;
    int wm = wave * 32;

    bf16x8 a[2][2];
#pragma unroll
    for (int i = 0; i < 2; ++i)
#pragma unroll
        for (int ks = 0; ks < 2; ++ks)
            a[i][ks] = *(bf16x8*)&As[wm + i * 16 + l16][ks * 32 + quad * 8];

    f32x4 acc[3][2][4];
#pragma unroll
    for (int o = 0; o < 3; ++o)
#pragma unroll
        for (int i = 0; i < 2; ++i)
#pragma unroll
            for (int j = 0; j < 4; ++j) acc[o][i][j] = (f32x4)0.f;

#pragma unroll
    for (int o = 0; o < 3; ++o)
#pragma unroll
        for (int j = 0; j < 4; ++j) {
            bf16x8 b0 = *(bf16x8*)&Wt[o][j * 16 + l16][quad * 8];
            bf16x8 b1 = *(bf16x8*)&Wt[o][j * 16 + l16][32 + quad * 8];
#pragma unroll
            for (int i = 0; i < 2; ++i) {
                acc[o][i][j] = __builtin_amdgcn_mfma_f32_16x16x32_bf16(a[i][0], b0, acc[o][i][j], 0, 0, 0);
                acc[o][i][j] = __builtin_amdgcn_mfma_f32_16x16x32_bf16(a[i][1], b1, acc[o][i][j], 0, 0, 0);
            }
        }

    bf16_t* outs[3] = { q, k, v };
    const float* biases[3] = { bq, bk, bv };
#pragma unroll
    for (int o = 0; o < 3; ++o)
#pragma unroll
        for (int j = 0; j < 4; ++j) {
            int col = j * 16 + l16;
            float bias = biases[o][col];
#pragma unroll
            for (int i = 0; i < 2; ++i) {
                long rbase = m0 + wm + i * 16 + quad * 4;
#pragma unroll
                for (int r = 0; r < 4; ++r)
                    outs[o][(rbase + r) * 64 + col] = (bf16_t)(acc[o][i][j][r] + bias);
            }
        }
}

// ---------------- causal flash attention, bf16 MFMA, 64q x 32kv tiles ----------------
__global__ __launch_bounds__(256) void attn_mfma_kernel(
    const bf16_t* __restrict__ Q, const bf16_t* __restrict__ K,
    const bf16_t* __restrict__ V, bf16_t* __restrict__ Ob)
{
    __shared__ bf16_t Ks[32][72];       // [kv][d], pad 8
    __shared__ bf16_t Vt[64][40];       // [d][kv], pad 8
    __shared__ bf16_t Ps[4][16][40];    // per-wave P tile [q][kv], pad 8

    int tid = threadIdx.x;
    int wave = tid >> 6, lane = tid & 63;
    int quad = lane >> 4, l16 = lane & 15;
    int q0 = blockIdx.x * 64;
    int bh = blockIdx.y;
    int b = bh >> 4, h = bh & 15;
    int qw = q0 + wave * 16;
    const float scale = 0.125f;             // 1/sqrt(64)
    const float MASKED = -1.25e19f;         // -1e20 * scale, per reference order

    const bf16_t* Qbase = Q + (((long)b * S_ + qw + l16) * H_ + h) * HD_;
    bf16x8 aq0 = *(const bf16x8*)&Qbase[quad * 8];
    bf16x8 aq1 = *(const bf16x8*)&Qbase[32 + quad * 8];

    float mrun[4], lrun[4];
    f32x4 oacc[4];
#pragma unroll
    for (int r = 0; r < 4; ++r) { mrun[r] = -3.0e38f; lrun[r] = 0.f; }
#pragma unroll
    for (int n = 0; n < 4; ++n) oacc[n] = (f32x4)0.f;

    int srow = tid >> 3, scol = (tid & 7) * 8;   // staging: 32 rows x 64 d
    int nkt = (q0 + 64) / 32;
    for (int kt = 0; kt < nkt; ++kt) {
        int k0 = kt * 32;
        __syncthreads();
        {
            long base = (((long)b * S_ + k0 + srow) * H_ + h) * HD_ + scol;
            *(bf16x8*)&Ks[srow][scol] = *(const bf16x8*)&K[base];
            bf16x8 vv = *(const bf16x8*)&V[base];
#pragma unroll
            for (int j = 0; j < 8; ++j) Vt[scol + j][srow] = vv[j];
        }
        __syncthreads();

        f32x4 sc[2];
        sc[0] = (f32x4)0.f; sc[1] = (f32x4)0.f;
#pragma unroll
        for (int n = 0; n < 2; ++n) {
            bf16x8 bk0 = *(bf16x8*)&Ks[n * 16 + l16][quad * 8];
            bf16x8 bk1 = *(bf16x8*)&Ks[n * 16 + l16][32 + quad * 8];
            sc[n] = __builtin_amdgcn_mfma_f32_16x16x32_bf16(aq0, bk0, sc[n], 0, 0, 0);
            sc[n] = __builtin_amdgcn_mfma_f32_16x16x32_bf16(aq1, bk1, sc[n], 0, 0, 0);
        }

        float alpha[4];
#pragma unroll
        for (int r = 0; r < 4; ++r) {
            int qg = qw + quad * 4 + r;
            float s0 = (k0 + l16      <= qg) ? sc[0][r] * scale : MASKED;
            float s1 = (k0 + 16 + l16 <= qg) ? sc[1][r] * scale : MASKED;
            float mt = fmaxf(s0, s1);
            mt = fmaxf(mt, __shfl_xor(mt, 1));
            mt = fmaxf(mt, __shfl_xor(mt, 2));
            mt = fmaxf(mt, __shfl_xor(mt, 4));
            mt = fmaxf(mt, __shfl_xor(mt, 8));
            float mnew = fmaxf(mrun[r], mt);
            float p0 = __expf(s0 - mnew);
            float p1 = __expf(s1 - mnew);
            float ls = p0 + p1;
            ls += __shfl_xor(ls, 1);
            ls += __shfl_xor(ls, 2);
            ls += __shfl_xor(ls, 4);
            ls += __shfl_xor(ls, 8);
            alpha[r] = __expf(mrun[r] - mnew);
            lrun[r] = lrun[r] * alpha[r] + ls;
            mrun[r] = mnew;
            int prow = quad * 4 + r;
            Ps[wave][prow][l16]      = (bf16_t)p0;
            Ps[wave][prow][16 + l16] = (bf16_t)p1;
        }
        bf16x8 ap = *(bf16x8*)&Ps[wave][l16][quad * 8];

#pragma unroll
        for (int n = 0; n < 4; ++n) {
            bf16x8 bv = *(bf16x8*)&Vt[n * 16 + l16][quad * 8];
            f32x4 c = oacc[n];
#pragma unroll
            for (int r = 0; r < 4; ++r) c[r] *= alpha[r];
            oacc[n] = __builtin_amdgcn_mfma_f32_16x16x32_bf16(ap, bv, c, 0, 0, 0);
        }
    }

#pragma unroll
    for (int r = 0; r < 4; ++r) {
        float inv = 1.0f / lrun[r];
        long rowbase = (((long)b * S_ + qw + quad * 4 + r) * H_ + h) * HD_;
#pragma unroll
        for (int n = 0; n < 4; ++n)
            Ob[rowbase + n * 16 + l16] = (bf16_t)(oacc[n][r] * inv);
    }
}

// ---------------- transpose + fp32->bf16 convert: W[Kd x Nd] -> Wt[Nd x Kd] ----------------
__global__ void tconv_kernel(const float* __restrict__ W, bf16_t* __restrict__ Wt,
                             int Kd, int Nd)
{
    __shared__ float t[32][33];
    int tx = threadIdx.x, ty = threadIdx.y;  // (32, 8)
    int bx = blockIdx.x, by = blockIdx.y;
#pragma unroll
    for (int i = 0; i < 4; ++i)
        t[ty + i * 8][tx] = W[(size_t)(by * 32 + ty + i * 8) * Nd + bx * 32 + tx];
    __syncthreads();
#pragma unroll
    for (int i = 0; i < 4; ++i)
        Wt[(size_t)(bx * 32 + ty + i * 8) * Kd + by * 32 + tx] = (bf16_t)t[tx][ty + i * 8];
}

// ---------------- bf16 MFMA GEMM: C[MxN] = A[MxK] * Bt[NxK]^T + bias ----------------
#define LDT 40
__global__ __launch_bounds__(256) void gemm_bt_kernel(
    const bf16_t* __restrict__ A, const bf16_t* __restrict__ Bt,
    const float* __restrict__ bias, float* __restrict__ Cf,
    bf16_t* __restrict__ Cb, int M, int N, int K, int act)
{
    __shared__ bf16_t As[128 * LDT];
    __shared__ bf16_t Bs[128 * LDT];
    int tid = threadIdx.x;
    int wave = tid >> 6, lane = tid & 63;
    int quad = lane >> 4, l16 = lane & 15;
    int m0 = blockIdx.x * 128;
    int n0 = blockIdx.y * 128;
    int wm = (wave >> 1) * 64, wn = (wave & 1) * 64;

    f32x4 acc[4][4];
#pragma unroll
    for (int i = 0; i < 4; ++i)
#pragma unroll
        for (int j = 0; j < 4; ++j) acc[i][j] = (f32x4)0.f;

    for (int k0 = 0; k0 < K; k0 += 32) {
        __syncthreads();
#pragma unroll
        for (int it = 0; it < 2; ++it) {
            int c = it * 256 + tid;          // [0,512)
            int row = c >> 2, col = (c & 3) * 8;
            *(bf16x8*)&As[row * LDT + col] =
                *(const bf16x8*)&A[(size_t)(m0 + row) * K + k0 + col];
            *(bf16x8*)&Bs[row * LDT + col] =
                *(const bf16x8*)&Bt[(size_t)(n0 + row) * K + k0 + col];
        }
        __syncthreads();

        bf16x8 af[4], bfr[4];
#pragma unroll
        for (int i = 0; i < 4; ++i)
            af[i] = *(bf16x8*)&As[(wm + i * 16 + l16) * LDT + quad * 8];
#pragma unroll
        for (int j = 0; j < 4; ++j)
            bfr[j] = *(bf16x8*)&Bs[(wn + j * 16 + l16) * LDT + quad * 8];
#pragma unroll
        for (int i = 0; i < 4; ++i)
#pragma unroll
            for (int j = 0; j < 4; ++j)
                acc[i][j] = __builtin_amdgcn_mfma_f32_16x16x32_bf16(
                    af[i], bfr[j], acc[i][j], 0, 0, 0);
    }

#pragma unroll
    for (int j = 0; j < 4; ++j) {
        int col = n0 + wn + j * 16 + l16;
        float bv = bias ? bias[col] : 0.f;
#pragma unroll
        for (int i = 0; i < 4; ++i) {
            int rbase = m0 + wm + i * 16 + quad * 4;
#pragma unroll
            for (int r = 0; r < 4; ++r) {
                float vv = acc[i][j][r] + bv;
                if (act == 1) vv = gelu_exact(vv);
                if (Cf) Cf[(size_t)(rbase + r) * N + col] = vv;
                if (Cb) Cb[(size_t)(rbase + r) * N + col] = (bf16_t)vv;
            }
        }
    }
}

// ---------------- fused residual add + LayerNorm (row = one block) ----------------
__global__ __launch_bounds__(256) void ln_fused_kernel(
    const float* __restrict__ a, const float* __restrict__ b,
    const float* __restrict__ w, const float* __restrict__ beta,
    float* __restrict__ out, bf16_t* __restrict__ outb)
{
    long row = blockIdx.x;
    int tid = threadIdx.x;
    f32x4 z = *(const f32x4*)&a[row * D_ + tid * 4];
    if (b) z += *(const f32x4*)&b[row * D_ + tid * 4];
    float s  = z[0] + z[1] + z[2] + z[3];
    float ss = z[0]*z[0] + z[1]*z[1] + z[2]*z[2] + z[3]*z[3];
#pragma unroll
    for (int off = 32; off >= 1; off >>= 1) {
        s  += __shfl_down(s, off);
        ss += __shfl_down(ss, off);
    }
    __shared__ float red[8];
    int lane = tid & 63, wid = tid >> 6;
    if (lane == 0) { red[wid * 2] = s; red[wid * 2 + 1] = ss; }
    __syncthreads();
    s  = red[0] + red[2] + red[4] + red[6];
    ss = red[1] + red[3] + red[5] + red[7];
    float mean = s * (1.0f / D_);
    float var  = ss * (1.0f / D_) - mean * mean;
    float rs = rsqrtf(var + 1e-5f);
    f32x4 wv = *(const f32x4*)&w[tid * 4];
    f32x4 bv = *(const f32x4*)&beta[tid * 4];
    f32x4 o = (z - mean) * rs * wv + bv;
    *(f32x4*)&out[row * D_ + tid * 4] = o;
    if (outb) *(bf16x4*)&outb[row * D_ + tid * 4] = __builtin_convertvector(o, bf16x4);
}

// ---------------- host launch ----------------
extern "C" void kernel_launch(void* const* d_in, const int* in_sizes, int n_in,
                              void* d_out, int out_size, void* d_ws, size_t ws_size,
                              hipStream_t stream)
{
    (void)in_sizes; (void)n_in; (void)out_size; (void)ws_size;
    const float* x    = (const float*)d_in[0];
    const float* pos  = (const float*)d_in[1];
    const float* Wq   = (const float*)d_in[2];
    const float* bq   = (const float*)d_in[3];
    const float* Wk   = (const float*)d_in[4];
    const float* bk   = (const float*)d_in[5];
    const float* Wv   = (const float*)d_in[6];
    const float* bv   = (const float*)d_in[7];
    const float* Wfc  = (const float*)d_in[8];
    const float* bfc  = (const float*)d_in[9];
    const float* ln1w = (const float*)d_in[10];
    const float* ln1b = (const float*)d_in[11];
    const float* ln2w = (const float*)d_in[12];
    const float* ln2b = (const float*)d_in[13];
    const float* W1   = (const float*)d_in[14];
    const float* b1   = (const float*)d_in[15];
    const float* W2   = (const float*)d_in[16];
    const float* b2   = (const float*)d_in[17];
    const float* lnfw = (const float*)d_in[18];
    const float* lnfb = (const float*)d_in[19];

    const size_t MB = 1 << 20;
    char* ws = (char*)d_ws;
    float*  y    = (float*)(ws);             //  0-8   fp32 activations
    bf16_t* yb   = (bf16_t*)(ws + 8 * MB);   //  8-12  bf16 activations
    bf16_t* qb   = (bf16_t*)(ws + 12 * MB);  // 12-16
    bf16_t* kb   = (bf16_t*)(ws + 16 * MB);  // 16-20
    bf16_t* vb   = (bf16_t*)(ws + 20 * MB);  // 20-24
    float*  t1   = (float*)(ws + 12 * MB);   // 12-20  (aliases qb/kb, free after attn)
    bf16_t* ob   = (bf16_t*)(ws + 24 * MB);  // 24-28
    float*  t2   = (float*)(ws + 20 * MB);   // 20-28  (aliases vb+ob, free after Wfc gemm)
    float*  add  = (float*)(ws + 28 * MB);   // 28-36
    bf16_t* addb = (bf16_t*)(ws + 36 * MB);  // 36-40
    bf16_t* ffb  = (bf16_t*)(ws + 40 * MB);  // 40-56
    bf16_t* WT   = (bf16_t*)(ws + 56 * MB);  // 56-64  per-layer weight transpose

    add_pos_kernel<<<2048, 256, 0, stream>>>(x, pos, y, yb);

    for (int i = 0; i < NL_; ++i) {
        qkv_mfma_kernel<<<256, 256, 0, stream>>>(
            yb, Wq + i * 4096, bq + i * 64, Wk + i * 4096, bk + i * 64,
            Wv + i * 4096, bv + i * 64, qb, kb, vb);

        attn_mfma_kernel<<<dim3(16, 32), 256, 0, stream>>>(qb, kb, vb, ob);

        tconv_kernel<<<dim3(32, 32), dim3(32, 8), 0, stream>>>(
            Wfc + (size_t)i * D_ * D_, WT, D_, D_);
        gemm_bt_kernel<<<dim3(16, 8), 256, 0, stream>>>(
            ob, WT, bfc + i * D_, t1, nullptr, 2048, D_, D_, 0);

        ln_fused_kernel<<<2048, 256, 0, stream>>>(
            t1, y, ln1w + i * D_, ln1b + i * D_, add, addb);

        tconv_kernel<<<dim3(128, 32), dim3(32, 8), 0, stream>>>(
            W1 + (size_t)i * D_ * DFF_, WT, D_, DFF_);
        gemm_bt_kernel<<<dim3(16, 32), 256, 0, stream>>>(
            addb, WT, b1 + i * DFF_, nullptr, ffb, 2048, DFF_, D_, 1);

        tconv_kernel<<<dim3(32, 128), dim3(32, 8), 0, stream>>>(
            W2 + (size_t)i * DFF_ * D_, WT, DFF_, D_);
        gemm_bt_kernel<<<dim3(16, 8), 256, 0, stream>>>(
            ffb, WT, b2 + i * D_, t2, nullptr, 2048, D_, DFF_, 0);

        ln_fused_kernel<<<2048, 256, 0, stream>>>(
            t2, add, ln2w + i * D_, ln2b + i * D_, y, yb);
    }

    ln_fused_kernel<<<2048, 256, 0, stream>>>(
        y, nullptr, lnfw, lnfb, (float*)d_out, nullptr);
}